// Round 22
// baseline (557.816 us; speedup 1.0000x reference)
//
#include <hip/hip_runtime.h>
#include <hip/hip_bf16.h>

#define BB 4096
#define SZ 32
#define DD 10000
#define DPAD 10240
#define NMOD 64
#define NROWS_M 128   // Mh(64) + Ml(64)
#define KSPLIT 4
#define NWORDS 160    // DPAD/64 packed words per row
#define STEPS 40      // KSEG/64
#define FIXCAP 1048576u

// ws layout (bytes) — total 22,020,096 (proven bound from round 12)
#define WS_BK_OFF    0u           // 160*128*64*2 = 2,621,440
#define WS_WH_OFF    2621440u     // 10240*32*2   =   655,360
#define WS_WL_OFF    3276800u     // 10240*32*2   =   655,360
#define WS_CPK_OFF   3932160u     // 160*64*8     =    81,920
#define WS_CNT_OFF   4014080u     // 64
#define WS_PACK_OFF  4194304u     // 160*4096*8   = 5,242,880
#define WS_CPART_OFF 9437184u     // 4*4096*128*4 = 8,388,608
#define WS_FIX_OFF   17825792u    // 1M*4         = 4,194,304  (end 22,020,096)

typedef __attribute__((ext_vector_type(4))) float f32x4;
typedef __attribute__((ext_vector_type(8))) short short8;

static __device__ __forceinline__ ushort f2bf(float f) {
    unsigned u = __builtin_bit_cast(unsigned, f);
    unsigned r = (u + 0x7fffu + ((u >> 16) & 1u)) >> 16;   // RNE
    return (ushort)r;
}
static __device__ __forceinline__ float bf2f(ushort h) {
    return __builtin_bit_cast(float, (unsigned)h << 16);
}

// exact sign pipeline: 1 iff cosf(t+bk)*sinf(t) > 0, else 0 (incl t==0 -> -1)
static __device__ __forceinline__ int sign_pm(float t, float bk) {
    if (t == 0.0f) return 0;
    const double INV_PI_D = 0.31830988618379067153776752674503;
    float v = t + bk;
    long long n1 = (long long)floor((double)t * INV_PI_D);
    long long n2 = (long long)floor(fma((double)v, INV_PI_D, 0.5));
    return (int)(((n1 + n2) & 1LL) ^ 1LL);
}

// expand 8 packed bits (bit=1 -> +1.0bf16, 0 -> -1.0bf16) into short8
static __device__ __forceinline__ short8 expand8(unsigned b) {
    unsigned nb = ~b;
    unsigned r0 = 0x3F803F80u | ((nb & 1u) << 15) | ((nb & 2u) << 30);
    unsigned r1 = 0x3F803F80u | (((nb >> 2) & 1u) << 15) | (((nb >> 2) & 2u) << 30);
    unsigned r2 = 0x3F803F80u | (((nb >> 4) & 1u) << 15) | (((nb >> 4) & 2u) << 30);
    unsigned r3 = 0x3F803F80u | (((nb >> 6) & 1u) << 15) | (((nb >> 6) & 2u) << 30);
    uint4 u = make_uint4(r0, r1, r2, r3);
    return __builtin_bit_cast(short8, u);
}

// ---------------- K0: build Bk [160][128][64] bf16 (Mh, Ml) ---------------
__global__ __launch_bounds__(256) void k0_build_B(
        const float* __restrict__ M, ushort* __restrict__ Bk) {
    int k = blockIdx.x * 256 + threadIdx.x;   // 0..10239
    int row = blockIdx.y;                      // 0..127
    ushort u = 0;
    if (k < DD) {
        float m = M[(size_t)(row & 63) * DD + k];
        ushort mh = f2bf(m);
        if (row < 64) {
            u = mh;
        } else {
            u = f2bf(m - bf2f(mh));
        }
    }
    int step = k >> 6, kk = k & 63;
    Bk[((size_t)step * NROWS_M + row) * 64 + kk] = u;
}

// ---------------- K0w: split W into bf16 hi/lo, zero fix counter ----------
__global__ __launch_bounds__(256) void k0w(
        const float* __restrict__ W, ushort* __restrict__ Wh,
        ushort* __restrict__ Wl, unsigned* __restrict__ cnt) {
    int idx = blockIdx.x * 256 + threadIdx.x;   // 0..327679 = 10240*32
    if (idx == 0) *cnt = 0u;
    int d = idx >> 5, j = idx & 31;
    float w = (d < DD) ? W[(size_t)d * SZ + j] : 0.f;
    ushort h = f2bf(w);
    Wh[idx] = h;
    Wl[idx] = f2bf(w - bf2f(h));
}

// ---------------- K0b: pack cluster signs -> cpackT [160][64] u64 ---------
__global__ __launch_bounds__(256) void k0b_pack_c(
        const float* __restrict__ cluster, unsigned long long* __restrict__ cpackT) {
    const int tid = threadIdx.x;
    const int lane = tid & 63;
    const int wv = __builtin_amdgcn_readfirstlane(tid >> 6);
    const int w = blockIdx.x * 4 + wv;        // 0..159
    const int kb = w * 64;
    unsigned long long myw = 0;
    for (int m = 0; m < 64; ++m) {
        int k = kb + lane;
        int bit = (k < DD) ? (cluster[(size_t)m * DD + k] > 0.f ? 1 : 0) : 0;
        unsigned long long bal = __ballot(bit);
        if (lane == m) myw = bal;
    }
    cpackT[(size_t)w * 64 + lane] = myw;
}

// ---------------- K1m: MFMA projection + guarded parity + pack ------------
// Per block: 16 rows x 2560 d (quarter). 4 waves x 10 iters x 64 d.
// t' = 4-pass split-bf16 MFMA (err <= ~1e-4 vs f32 T_G dot); parity via
// f32 floors with EPS=2.5e-4 guard band; risky elements -> fix list.
__global__ __launch_bounds__(256, 3) void k1m(
        const float* __restrict__ x, const ushort* __restrict__ Wh,
        const ushort* __restrict__ Wl, const float* __restrict__ bias,
        float* __restrict__ enc_out, unsigned long long* __restrict__ packedT,
        unsigned* __restrict__ cnt, unsigned* __restrict__ fixbuf) {
    const int tid = threadIdx.x;
    const int lane = tid & 63;
    const int wv = tid >> 6;
    const int fr = lane & 15;
    const int fg = lane >> 4;
    const int i0 = blockIdx.x * 16;
    const int quarter = blockIdx.y;

    // A fragment: x row (i0+fr), k = fg*8..+7, bf16 hi/lo split
    short8 xh8, xl8;
    {
        const float* xp = x + (size_t)(i0 + fr) * SZ + fg * 8;
        #pragma unroll
        for (int e = 0; e < 8; ++e) {
            float xv = xp[e];
            ushort hh = f2bf(xv);
            ushort ll = f2bf(xv - bf2f(hh));
            xh8[e] = (short)hh;
            xl8[e] = (short)ll;
        }
    }

    const float INV_PI_F = 0.31830988618379067f;
    const float EPS = 2.5e-4f;

    for (int it = 0; it < 10; ++it) {
        const int dblk = quarter * 40 + it * 4 + wv;    // 0..159
        const int db = dblk * 64;
        unsigned long long bal[4][4];
        #pragma unroll
        for (int ta = 0; ta < 4; ++ta) {
            const int d = db + ta * 16 + fr;
            const short8 wh = *reinterpret_cast<const short8*>(Wh + (size_t)d * SZ + fg * 8);
            const short8 wl = *reinterpret_cast<const short8*>(Wl + (size_t)d * SZ + fg * 8);
            f32x4 a = {0.f, 0.f, 0.f, 0.f};
            a = __builtin_amdgcn_mfma_f32_16x16x32_bf16(xl8, wl, a, 0, 0, 0);
            a = __builtin_amdgcn_mfma_f32_16x16x32_bf16(xl8, wh, a, 0, 0, 0);
            a = __builtin_amdgcn_mfma_f32_16x16x32_bf16(xh8, wl, a, 0, 0, 0);
            a = __builtin_amdgcn_mfma_f32_16x16x32_bf16(xh8, wh, a, 0, 0, 0);
            const bool care = (d < DD);
            const float bb = bias[care ? d : 0];
            #pragma unroll
            for (int r = 0; r < 4; ++r) {
                float t = a[r];
                float u1 = t * INV_PI_F;
                float f1 = floorf(u1);
                float d1 = u1 - f1;
                float v = t + bb;
                float u2 = fmaf(v, INV_PI_F, 0.5f);
                float f2 = floorf(u2);
                float d2 = u2 - f2;
                bool risky = (d1 < EPS) | (d1 > 1.f - EPS) |
                             (d2 < EPS) | (d2 > 1.f - EPS);
                int e = ((((int)f1 + (int)f2) & 1) ^ 1);
                e = care ? e : 0;
                bal[ta][r] = __ballot(e);              // full-wave, convergent
                const int irow = i0 + fg * 4 + r;
                if (care) {
                    enc_out[(size_t)irow * DD + d] = e ? 1.f : -1.f;
                    if (risky) {
                        unsigned idx = atomicAdd(cnt, 1u);
                        if (idx < FIXCAP)
                            fixbuf[idx] = (unsigned)irow * 16384u + (unsigned)d;
                    }
                }
            }
        }
        // assemble row-major packed words from the 16 ballots
        const int il = lane & 15;
        const int rr = il & 3;
        const int fgs = il >> 2;
        unsigned long long word = 0;
        #pragma unroll
        for (int ta = 0; ta < 4; ++ta) {
            unsigned long long b = (rr == 0) ? bal[ta][0] : (rr == 1) ? bal[ta][1]
                                 : (rr == 2) ? bal[ta][2] : bal[ta][3];
            word |= ((b >> (fgs * 16)) & 0xFFFFull) << (ta * 16);
        }
        if (lane < 16) packedT[(size_t)dblk * BB + i0 + il] = word;
    }
}

// ---------------- K1c: exact fix-up of risky elements ---------------------
__global__ __launch_bounds__(256) void k1c(
        const float* __restrict__ x, const float* __restrict__ W,
        const float* __restrict__ bias, const unsigned* __restrict__ cnt,
        const unsigned* __restrict__ fixbuf, float* __restrict__ enc_out,
        unsigned long long* __restrict__ packedT) {
    unsigned n = *cnt;
    if (n > FIXCAP) n = FIXCAP;
    for (unsigned j = blockIdx.x * 256 + threadIdx.x; j < n; j += gridDim.x * 256) {
        unsigned code = fixbuf[j];
        int i = (int)(code >> 14);
        int d = (int)(code & 16383u);
        const float* xp = x + (size_t)i * SZ;
        const float* wp = W + (size_t)d * SZ;
        float g0 = 0.f, g1 = 0.f, g2 = 0.f, g3 = 0.f;
        #pragma unroll
        for (int q = 0; q < 8; ++q) {
            g0 = fmaf(wp[4 * q + 0], xp[4 * q + 0], g0);
            g1 = fmaf(wp[4 * q + 1], xp[4 * q + 1], g1);
            g2 = fmaf(wp[4 * q + 2], xp[4 * q + 2], g2);
            g3 = fmaf(wp[4 * q + 3], xp[4 * q + 3], g3);
        }
        float t = (g0 + g1) + (g2 + g3);
        int e = sign_pm(t, bias[d]);
        enc_out[(size_t)i * DD + d] = e ? 1.f : -1.f;
        unsigned long long* wordp = packedT + (size_t)(d >> 6) * BB + i;
        unsigned long long bit = 1ull << (d & 63);
        if (e) atomicOr(wordp, bit);
        else   atomicAnd(wordp, ~bit);
    }
}

// ---------------- K2: fragment-direct MFMA GEMM, M-part only --------------
__global__ __launch_bounds__(256, 2) void k2_gemm(
        const unsigned long long* __restrict__ packedT,  // [160][4096]
        const ushort* __restrict__ Bk,                   // [160][128][64]
        float* __restrict__ Cpart) {
    const int tid = threadIdx.x;
    const int wid = tid >> 6;
    const int lane = tid & 63;
    const int fr = lane & 15;
    const int fg = lane >> 4;

    const int row0 = blockIdx.x * 64;
    const int seg = blockIdx.y;
    const int wcol = wid * 32;

    const unsigned long long* pA = packedT + (size_t)(seg * STEPS) * BB + row0 + fr;
    const ushort* pB = Bk + ((size_t)(seg * STEPS) * NROWS_M + wcol + fr) * 64 + fg * 8;

    f32x4 acc[4][2] = {};
    unsigned long long aw0[4], aw1[4];
    uint4 b0[2][2], b1[2][2];

#define LOADA(dst, s)                                         \
    _Pragma("unroll")                                         \
    for (int mt = 0; mt < 4; ++mt)                            \
        dst[mt] = pA[(size_t)(s) * BB + mt * 16];

#define LOADB(dst, s)                                         \
    _Pragma("unroll")                                         \
    for (int n = 0; n < 2; ++n) {                             \
        const ushort* p = pB + ((size_t)(s) * NROWS_M + n * 16) * 64; \
        dst[n][0] = *reinterpret_cast<const uint4*>(p);       \
        dst[n][1] = *reinterpret_cast<const uint4*>(p + 32);  \
    }

#define COMPUTE(aw, bf)                                       \
    _Pragma("unroll")                                         \
    for (int mt = 0; mt < 4; ++mt) {                          \
        unsigned lo = (unsigned)aw[mt];                       \
        unsigned hi = (unsigned)(aw[mt] >> 32);               \
        short8 af0 = expand8((lo >> (fg * 8)) & 0xffu);       \
        short8 af1 = expand8((hi >> (fg * 8)) & 0xffu);       \
        _Pragma("unroll")                                     \
        for (int n = 0; n < 2; ++n) {                         \
            acc[mt][n] = __builtin_amdgcn_mfma_f32_16x16x32_bf16( \
                af0, __builtin_bit_cast(short8, bf[n][0]), acc[mt][n], 0, 0, 0); \
            acc[mt][n] = __builtin_amdgcn_mfma_f32_16x16x32_bf16( \
                af1, __builtin_bit_cast(short8, bf[n][1]), acc[mt][n], 0, 0, 0); \
        }                                                     \
    }

    LOADA(aw0, 0)
    LOADB(b0, 0)

    for (int s = 0; s < STEPS; s += 2) {
        LOADA(aw1, s + 1)
        LOADB(b1, s + 1)
        COMPUTE(aw0, b0)
        if (s + 2 < STEPS) {
            LOADA(aw0, s + 2)
            LOADB(b0, s + 2)
        }
        COMPUTE(aw1, b1)
    }

    #pragma unroll
    for (int mt = 0; mt < 4; ++mt)
        #pragma unroll
        for (int n = 0; n < 2; ++n)
            #pragma unroll
            for (int r = 0; r < 4; ++r) {
                int grow = row0 + mt * 16 + fg * 4 + r;
                int col = wcol + n * 16 + fr;
                Cpart[((size_t)seg * BB + grow) * NROWS_M + col] = acc[mt][n][r];
            }
#undef LOADA
#undef LOADB
#undef COMPUTE
}

// ---------------- K3: popcount-sim + reduce + softmax + combine -----------
__global__ __launch_bounds__(256) void k3_final(
        const unsigned long long* __restrict__ packedT,
        const unsigned long long* __restrict__ cpackT,
        const float* __restrict__ Cpart, float* __restrict__ res) {
    const int tid = threadIdx.x;
    const int lane = tid & 63;                 // model index
    const int wv = __builtin_amdgcn_readfirstlane(tid >> 6);
    const int row = blockIdx.x * 4 + wv;

    int mis = 0;
    const unsigned long long* ap = packedT + row;
    const unsigned long long* cp = cpackT + lane;
    for (int w = 0; w < NWORDS; ++w) {
        unsigned long long a = ap[(size_t)w * BB];     // wave-uniform
        unsigned long long c = cp[(size_t)w * 64];
        mis += __popcll(a ^ c);
    }
    float sim = (float)(DD - 2 * mis) * 1e-4f;

    float mh = 0.f, ml = 0.f;
    #pragma unroll
    for (int seg = 0; seg < KSPLIT; ++seg) {
        const float* base = Cpart + ((size_t)seg * BB + row) * NROWS_M;
        mh += base[lane];
        ml += base[64 + lane];
    }
    float mr = mh + ml;

    float mx = sim;
    #pragma unroll
    for (int o = 32; o; o >>= 1) mx = fmaxf(mx, __shfl_xor(mx, o, 64));
    float e = expf(sim - mx);
    float num = e * mr;
    float Z = e;
    #pragma unroll
    for (int o = 32; o; o >>= 1) {
        Z += __shfl_xor(Z, o, 64);
        num += __shfl_xor(num, o, 64);
    }
    if (lane == 0) res[row] = num / Z;
}

extern "C" void kernel_launch(void* const* d_in, const int* in_sizes, int n_in,
                              void* d_out, int out_size, void* d_ws, size_t ws_size,
                              hipStream_t stream) {
    const float* x = (const float*)d_in[0];
    const float* W = (const float*)d_in[1];
    const float* bias = (const float*)d_in[2];
    const float* M = (const float*)d_in[3];
    const float* cluster = (const float*)d_in[4];

    float* res = (float*)d_out;            // [4096]
    float* enc = (float*)d_out + BB;       // [4096][10000]

    ushort* Bk = (ushort*)((char*)d_ws + WS_BK_OFF);
    ushort* Wh = (ushort*)((char*)d_ws + WS_WH_OFF);
    ushort* Wl = (ushort*)((char*)d_ws + WS_WL_OFF);
    unsigned long long* cpackT = (unsigned long long*)((char*)d_ws + WS_CPK_OFF);
    unsigned* cnt = (unsigned*)((char*)d_ws + WS_CNT_OFF);
    unsigned long long* packedT = (unsigned long long*)((char*)d_ws + WS_PACK_OFF);
    float* Cpart = (float*)((char*)d_ws + WS_CPART_OFF);
    unsigned* fixbuf = (unsigned*)((char*)d_ws + WS_FIX_OFF);

    k0_build_B<<<dim3(40, NROWS_M), 256, 0, stream>>>(M, Bk);
    k0w<<<1280, 256, 0, stream>>>(W, Wh, Wl, cnt);
    k0b_pack_c<<<40, 256, 0, stream>>>(cluster, cpackT);
    k1m<<<dim3(256, 4), 256, 0, stream>>>(x, Wh, Wl, bias, enc, packedT, cnt, fixbuf);
    k1c<<<128, 256, 0, stream>>>(x, W, bias, cnt, fixbuf, enc, packedT);
    k2_gemm<<<dim3(64, KSPLIT), 256, 0, stream>>>(packedT, Bk, Cpart);
    k3_final<<<BB / 4, 256, 0, stream>>>(packedT, cpackT, Cpart, res);
}